// Round 11
// baseline (1114.333 us; speedup 1.0000x reference)
//
#include <hip/hip_runtime.h>
#include <hip/hip_bf16.h>
#include <math.h>

namespace {

constexpr int Bn = 8;
constexpr int Nn = 729;
constexpr int Cn = 1152;
constexpr int Hn = 16;
constexpr int Dn = 72;
constexpr int Fn = 4304;
constexpr int Rn = 23;
constexpr int NAn = 365;              // even tokens (src half)
constexpr int NBn = 364;              // odd tokens (dst half)
constexpr int NMn = 706;              // N - R merged tokens
constexpr int UNMn = NAn - Rn;        // 342 unmerged
constexpr float EPSf = 1e-6f;
constexpr float SCALEf = 0.11785113019775793f;  // 72^-0.5

using bf16 = __hip_bfloat16;
typedef short v8s __attribute__((ext_vector_type(8)));
typedef float v4f __attribute__((ext_vector_type(4)));

__device__ __forceinline__ float toF(bf16 v) { return __bfloat162float(v); }
__device__ __forceinline__ void stF(float* p, float v) { *p = v; }
__device__ __forceinline__ void stF(bf16* p, float v) { *p = __float2bfloat16(v); }

__device__ __forceinline__ float geluf(float x) {
  float x3 = x * x * x;
  return 0.5f * x * (1.f + tanhf(0.7978845608028654f * (x + 0.044715f * x3)));
}

__device__ __forceinline__ int clampi(int v, int lo, int hi) {
  return v < lo ? lo : (v > hi ? hi : v);
}

// async global -> LDS, 16B per lane; LDS dest is wave-uniform base + lane*16
__device__ __forceinline__ void gl_lds16(const bf16* __restrict__ g, short* l) {
  __builtin_amdgcn_global_load_lds(
      (const __attribute__((address_space(1))) void*)g,
      (__attribute__((address_space(3))) void*)l, 16, 0, 0);
}

// -------- LN stats: one block per row; fp32 (value path) + optional fp64 (decision path) --------
__global__ __launch_bounds__(256) void ln_stats_kernel(const float* __restrict__ x,
                                                       float* __restrict__ sf,
                                                       double* __restrict__ sd,
                                                       int rows) {
  int row = blockIdx.x;
  if (row >= rows) return;
  const float* xr = x + (size_t)row * Cn;
  double s = 0.0, s2 = 0.0;
  for (int c = threadIdx.x; c < Cn; c += 256) {
    double v = (double)xr[c];
    s += v; s2 += v * v;
  }
  __shared__ double sh[8];
#pragma unroll
  for (int o = 32; o > 0; o >>= 1) { s += __shfl_down(s, o); s2 += __shfl_down(s2, o); }
  int w = threadIdx.x >> 6;
  if ((threadIdx.x & 63) == 0) { sh[w] = s; sh[4 + w] = s2; }
  __syncthreads();
  if (threadIdx.x == 0) {
    double ts = sh[0] + sh[1] + sh[2] + sh[3];
    double ts2 = sh[4] + sh[5] + sh[6] + sh[7];
    double mean = ts / Cn;
    double var = ts2 / Cn - mean * mean;
    double rstd = 1.0 / sqrt(var + (double)EPSf);
    sf[2 * row] = (float)mean;
    sf[2 * row + 1] = (float)rstd;
    if (sd) { sd[2 * row] = mean; sd[2 * row + 1] = rstd; }
  }
}

// -------- LN apply -> bf16 tensor --------
__global__ __launch_bounds__(256) void ln_apply_kernel(const float* __restrict__ x,
                                                       const float* __restrict__ stats,
                                                       const float* __restrict__ g,
                                                       const float* __restrict__ b,
                                                       bf16* __restrict__ y) {
  int row = blockIdx.x;
  float mean = stats[2 * row], rstd = stats[2 * row + 1];
  const float* xr = x + (size_t)row * Cn;
  bf16* yr = y + (size_t)row * Cn;
  for (int c = threadIdx.x; c < Cn; c += 256)
    yr[c] = __float2bfloat16((xr[c] - mean) * rstd * g[c] + b[c]);
}

// -------- Weight transpose+convert: W[K][N] fp32 -> Wt[N][K] bf16 (x scale) --------
__global__ __launch_bounds__(256) void wconv_kernel(const float* __restrict__ W,
                                                    bf16* __restrict__ Wt,
                                                    int K, int N, float scale) {
  __shared__ float tile[32][33];
  int kt = blockIdx.y * 32, nt = blockIdx.x * 32;
  int tx = threadIdx.x & 31, ty = threadIdx.x >> 5;  // ty 0..7
#pragma unroll
  for (int yy = 0; yy < 4; ++yy) {
    int k = kt + ty * 4 + yy, n = nt + tx;
    tile[ty * 4 + yy][tx] = (k < K && n < N) ? W[(size_t)k * N + n] : 0.f;
  }
  __syncthreads();
#pragma unroll
  for (int yy = 0; yy < 4; ++yy) {
    int n = nt + ty * 4 + yy, k = kt + tx;
    if (n < N && k < K) Wt[(size_t)n * K + k] = __float2bfloat16(tile[tx][ty * 4 + yy] * scale);
  }
}

// -------- scale/copy a float vector --------
__global__ __launch_bounds__(256) void vscale_kernel(const float* __restrict__ in,
                                                     float* __restrict__ out, int n, float s) {
  int i = blockIdx.x * 256 + threadIdx.x;
  if (i < n) out[i] = in[i] * s;
}

// -------- MFMA GEMM (BM x BN tiles, swizzled 1D grid, BK=64, XOR-swizzled LDS) -----------------
// Round-10: BT=64 runs only 8 MFMA/wave (~40cy) between barrier pairs (~150cy drain) -> util
// capped ~20%. Rectangular BM=128 x BN=64 doubles MFMA/barrier (16/wave/step) while keeping the
// grid fat on N=1152 GEMMs (fc2 810 / QKV 2484 blocks). LDS (BM+BN)*128B = 24.5KB.
// LDS XOR-swizzle per rule #21 (both-sides-or-neither with global_load_lds):
//  physical chunk = logical ^ (row&7); interior pre-swizzles the per-lane GLOBAL source;
//  reads use ((ks2*4+quad)^(l16&7)) -> conflict-free (round-10: 4.2e7 -> GEMMs left top-5).
// Tile order: m204 bijective XCD-chunking + GROUP_M serpentine (GM=3 at BM=128: 3x128 rows x
// K=4304 x 2B = 3.3MB fits one XCD L2). Optional 3-way column-split epilogue (QKV fusion).
template <typename OT, int BM, int BN>
__global__ __launch_bounds__(256) void mfma_gemm(const bf16* __restrict__ A,
                                                 const bf16* __restrict__ Wt,
                                                 const float* __restrict__ bias,
                                                 const float* __restrict__ resid,
                                                 OT* __restrict__ Cout,
                                                 OT* __restrict__ C2,
                                                 OT* __restrict__ C3,
                                                 int M, int N, int K, int act) {
  constexpr int FRm = BM / 32;      // row frags per wave
  constexpr int FRn = BN / 32;      // col frags per wave
  constexpr int GM = (BM >= 128) ? 3 : 6;  // row-panel group (L2 working set ~3.3MB)
  __align__(16) __shared__ short As[BM * 64];
  __align__(16) __shared__ short Bs[BN * 64];
  // ---- tile decode ----
  int nx = (N + BN - 1) / BN, ny = (M + BM - 1) / BM;
  int nwg = nx * ny;                // == gridDim.x
  int blk = blockIdx.x;
  int q8 = nwg >> 3, r8 = nwg & 7;
  int xcd = blk & 7, slot = blk >> 3;
  int wgid = (xcd < r8 ? xcd * (q8 + 1) : r8 * (q8 + 1) + (xcd - r8) * q8) + slot;
  int npg = GM * nx;
  int gid = wgid / npg;
  int rem = wgid - gid * npg;
  int m0 = gid * GM;
  int gsz = ny - m0; if (gsz > GM) gsz = GM;
  int by = m0 + rem % gsz;
  int bx = rem / gsz;
  int bm = by * BM, bn = bx * BN;
  // ---- per-thread ids ----
  int tid = threadIdx.x;
  int lane = tid & 63, w = tid >> 6;
  int wm = w >> 1, wn = w & 1;
  int l16 = lane & 15, quad = lane >> 4;
  int lr8 = lane >> 3;
  int lc8s = (((lane & 7) ^ (lane >> 3)) * 8);   // swizzled global chunk for gl_lds staging
  bool interior = (bm + BM <= M) && (bn + BN <= N);
  v4f acc[FRm][FRn];
#pragma unroll
  for (int i = 0; i < FRm; ++i)
#pragma unroll
    for (int j = 0; j < FRn; ++j) acc[i][j] = (v4f){0.f, 0.f, 0.f, 0.f};
  int ksteps = (K + 63) / 64;
  for (int ks = 0; ks < ksteps; ++ks) {
    int k0 = ks * 64;
    __syncthreads();
    if (interior && (k0 + 64 <= K)) {
#pragma unroll
      for (int h2 = 0; h2 < BM / 32; ++h2) {
        int rb = w * (BM / 4) + h2 * 8;   // multiple of 8 -> row&7 == lane>>3
        gl_lds16(A + (size_t)(bm + rb + lr8) * K + k0 + lc8s, &As[rb * 64]);
      }
#pragma unroll
      for (int h2 = 0; h2 < BN / 32; ++h2) {
        int rb = w * (BN / 4) + h2 * 8;
        gl_lds16(Wt + (size_t)(bn + rb + lr8) * K + k0 + lc8s, &Bs[rb * 64]);
      }
    } else {
#pragma unroll
      for (int p = 0; p < BM / 32; ++p) {
        int idx = tid + p * 256;
        int r = idx >> 3, pc = idx & 7;
        int cg = (pc ^ (r & 7)) * 8;      // logical chunk stored at physical pc
        int4 za = {0, 0, 0, 0};
        if (k0 + cg < K && bm + r < M)    // K%8==0 so group-granular guard is exact
          za = *reinterpret_cast<const int4*>(A + (size_t)(bm + r) * K + k0 + cg);
        *reinterpret_cast<int4*>(&As[r * 64 + pc * 8]) = za;
      }
#pragma unroll
      for (int p = 0; p < BN / 32; ++p) {
        int idx = tid + p * 256;
        int r = idx >> 3, pc = idx & 7;
        int cg = (pc ^ (r & 7)) * 8;
        int4 zb = {0, 0, 0, 0};
        if (k0 + cg < K && bn + r < N)
          zb = *reinterpret_cast<const int4*>(Wt + (size_t)(bn + r) * K + k0 + cg);
        *reinterpret_cast<int4*>(&Bs[r * 64 + pc * 8]) = zb;
      }
    }
    __syncthreads();
#pragma unroll
    for (int ks2 = 0; ks2 < 2; ++ks2) {
      int pcr = ((ks2 * 4 + quad) ^ (l16 & 7)) * 8;  // swizzled read chunk (row&7 == l16&7)
      v8s af[FRm], bfr[FRn];
#pragma unroll
      for (int i = 0; i < FRm; ++i)
        af[i] = *reinterpret_cast<const v8s*>(
            &As[(wm * (BM / 2) + i * 16 + l16) * 64 + pcr]);
#pragma unroll
      for (int j = 0; j < FRn; ++j)
        bfr[j] = *reinterpret_cast<const v8s*>(
            &Bs[(wn * (BN / 2) + j * 16 + l16) * 64 + pcr]);
#pragma unroll
      for (int i = 0; i < FRm; ++i)
#pragma unroll
        for (int j = 0; j < FRn; ++j)
          acc[i][j] = __builtin_amdgcn_mfma_f32_16x16x32_bf16(af[i], bfr[j], acc[i][j], 0, 0, 0);
    }
  }
  int w3 = C2 ? (N / 3) : 0;
#pragma unroll
  for (int i = 0; i < FRm; ++i) {
#pragma unroll
    for (int j = 0; j < FRn; ++j) {
#pragma unroll
      for (int r = 0; r < 4; ++r) {
        int row = bm + wm * (BM / 2) + i * 16 + quad * 4 + r;
        int col = bn + wn * (BN / 2) + j * 16 + l16;
        if (row < M && col < N) {
          float v = acc[i][j][r] + bias[col];
          if (act) v = geluf(v);
          if (resid) v += resid[(size_t)row * N + col];
          if (C2) {
            int seg = col / w3, c2 = col - seg * w3;
            OT* d = (seg == 0) ? Cout : (seg == 1 ? C2 : C3);
            stF(&d[(size_t)row * w3 + c2], v);
          } else {
            stF(&Cout[(size_t)row * N + col], v);
          }
        }
      }
    }
  }
}

// -------- V transpose (one-shot): vb[b,n,h*D+d] -> vt[(b*H+h)*80 + d][768 keys] --------
// d-rows padded 72->80 (zeros), keys padded 729->768 (zeros). Padded-LDS tile transpose.
constexpr int NKP = 768;  // padded key count (12 tiles x 64)
__global__ __launch_bounds__(256) void vtrans_kernel(const bf16* __restrict__ v,
                                                     bf16* __restrict__ vt) {
  int kb = blockIdx.x % 12;   // 64-key block
  int bh = blockIdx.x / 12;
  int h = bh % Hn, b = bh / Hn;
  __shared__ short Ts[64][73];  // +1 short pad: stride 146B -> ~2-way on column reads
  int tid = threadIdx.x;
  // load 64 keys x 72 d (scalar, coalesced on d)
#pragma unroll
  for (int i = 0; i < 18; ++i) {
    int idx = tid + i * 256;  // < 4608
    int key = idx / 72, d = idx % 72;
    int kg = kb * 64 + key;
    bf16 val = (kg < Nn) ? v[((size_t)(b * Nn + kg)) * Cn + h * Dn + d] : bf16(0.f);
    Ts[key][d] = *reinterpret_cast<short*>(&val);
  }
  __syncthreads();
  // write 72 d-rows x 64 keys (scalar, coalesced on key)
#pragma unroll
  for (int i = 0; i < 18; ++i) {
    int idx = tid + i * 256;
    int d = idx / 64, key = idx % 64;
    vt[((size_t)bh * 80 + d) * NKP + kb * 64 + key] = *reinterpret_cast<bf16*>(&Ts[key][d]);
  }
  // zero pad rows d=72..79
  for (int i = tid; i < 8 * 64; i += 256) {
    int d = 72 + i / 64, key = i % 64;
    vt[((size_t)bh * 80 + d) * NKP + kb * 64 + key] = bf16(0.f);
  }
}

// -------- MFMA flash attention: one block = (b, h, 64-query tile); in-place over q --------
// Round-2 structure + T14 reg-prefetch + __expf + fast-path mask. Round-10 post-mortem:
// the XCD batch-pinning (b=blk&7) cut FETCH 149->49MB but COST 18us (attn is latency-bound
// at 5% HBM; pinning 192 blocks to one 32-CU XCD hurt balance/occupancy 33->23%). Reverted.
constexpr int ATQ = 64, ATK = 64;
constexpr int NQT2 = (Nn + ATQ - 1) / ATQ;  // 12
constexpr int NKT = 12;                     // 64-key tiles
constexpr int KSS = 104, VTS = 72, PSS = 72;

__device__ __forceinline__ void attn_load_tile(const bf16* __restrict__ k,
                                               const bf16* __restrict__ vt,
                                               int b, int bh, int h, int kt_, int tid,
                                               int4* kr, int4* vr) {
#pragma unroll
  for (int i = 0; i < 3; ++i) {
    int idx = tid + i * 256;
    int r = idx / 12, ch = idx % 12;
    int kg = kt_ + r;
    int4 z = {0, 0, 0, 0};
    if (ch < 9 && kg < Nn)
      z = *reinterpret_cast<const int4*>(k + ((size_t)(b * Nn + kg)) * Cn + h * Dn + ch * 8);
    kr[i] = z;
    if (idx < 640) {
      int d = idx >> 3, kc = idx & 7;
      vr[i] = *reinterpret_cast<const int4*>(vt + ((size_t)bh * 80 + d) * NKP + kt_ + kc * 8);
    }
  }
}

__global__ __launch_bounds__(256) void attn_mfma_kernel(bf16* q /* in: q, out: attn */,
                                                        const bf16* __restrict__ k,
                                                        const bf16* __restrict__ vt,
                                                        const float* __restrict__ mask) {
  int blk = blockIdx.x;
  int qt = blk % NQT2;
  int bh = blk / NQT2;
  int h = bh % Hn;
  int b = bh / Hn;
  __align__(16) __shared__ short Ks[ATK * KSS];
  __align__(16) __shared__ short Vt[80 * VTS];
  __align__(16) __shared__ short Ps[4][16 * PSS];
  int tid = threadIdx.x;
  int lane = tid & 63, w = tid >> 6;
  int l16 = lane & 15, quad = lane >> 4;

  // Q fragments straight to registers (each wave only ever needs its own 16 rows)
  v8s aq[3];
  int qg_l = qt * ATQ + w * 16 + l16;
  {
    const bf16* qrow = q + ((size_t)(b * Nn + (qg_l < Nn ? qg_l : 0))) * Cn + h * Dn;
#pragma unroll
    for (int ks = 0; ks < 3; ++ks) {
      bool valid = (qg_l < Nn) && (ks < 2 || quad == 0);  // ks=2: d=64..71 only for quad 0
      if (valid)
        aq[ks] = *reinterpret_cast<const v8s*>(qrow + ks * 32 + quad * 8);
      else
        aq[ks] = (v8s){0, 0, 0, 0, 0, 0, 0, 0};
    }
  }

  v4f o[5];
#pragma unroll
  for (int dj = 0; dj < 5; ++dj) o[dj] = (v4f){0.f, 0.f, 0.f, 0.f};
  float m_r[4] = {-INFINITY, -INFINITY, -INFINITY, -INFINITY};
  float l_r[4] = {0.f, 0.f, 0.f, 0.f};  // per-lane partial; reduced at end

  int4 kr[3], vr[3];
  attn_load_tile(k, vt, b, bh, h, 0, tid, kr, vr);

  for (int t = 0; t < NKT; ++t) {
    int kt2 = t * ATK;
    __syncthreads();  // previous tile's LDS reads complete
    // regs -> LDS (write-late half of T14 split)
#pragma unroll
    for (int i = 0; i < 3; ++i) {
      int idx = tid + i * 256;
      int r = idx / 12, ch = idx % 12;
      *reinterpret_cast<int4*>(&Ks[r * KSS + ch * 8]) = kr[i];
      if (idx < 640) {
        int d = idx >> 3, kc = idx & 7;
        *reinterpret_cast<int4*>(&Vt[d * VTS + kc * 8]) = vr[i];
      }
    }
    __syncthreads();
    // issue next tile's global loads early; latency hides under compute below
    if (t + 1 < NKT) attn_load_tile(k, vt, b, bh, h, kt2 + ATK, tid, kr, vr);

    // QK^T: S[16q x 64k] per wave, 12 MFMA (scores arrive pre-scaled)
    v4f sfr[4];
#pragma unroll
    for (int j = 0; j < 4; ++j) sfr[j] = (v4f){0.f, 0.f, 0.f, 0.f};
#pragma unroll
    for (int ks = 0; ks < 3; ++ks) {
#pragma unroll
      for (int j = 0; j < 4; ++j) {
        v8s bk_ = *reinterpret_cast<const v8s*>(&Ks[(j * 16 + l16) * KSS + ks * 32 + quad * 8]);
        sfr[j] = __builtin_amdgcn_mfma_f32_16x16x32_bf16(aq[ks], bk_, sfr[j], 0, 0, 0);
      }
    }
    // + mask (C layout: col=j*16+l16, row=quad*4+r); fast path for full tiles
    float sv[4][4];
    int qbase = qt * ATQ + w * 16 + quad * 4;
    bool tfull = (kt2 + ATK <= Nn);
#pragma unroll
    for (int r = 0; r < 4; ++r) {
      int qg = qbase + r;
      const float* mrow = mask + ((size_t)(b * Nn + (qg < Nn ? qg : 0))) * Nn;
      if (tfull && qg < Nn) {
#pragma unroll
        for (int j = 0; j < 4; ++j) sv[j][r] = sfr[j][r] + mrow[kt2 + j * 16 + l16];
      } else {
#pragma unroll
        for (int j = 0; j < 4; ++j) {
          int kg = kt2 + j * 16 + l16;
          sv[j][r] = (kg < Nn && qg < Nn) ? sfr[j][r] + mrow[kg] : -INFINITY;
        }
      }
    }
    // online softmax per row: max reduce across the 16-lane group; l stays per-lane partial
    float alpha[4];
#pragma unroll
    for (int r = 0; r < 4; ++r) {
      float mx = fmaxf(fmaxf(sv[0][r], sv[1][r]), fmaxf(sv[2][r], sv[3][r]));
#pragma unroll
      for (int o2 = 1; o2 < 16; o2 <<= 1) mx = fmaxf(mx, __shfl_xor(mx, o2));
      float mnew = fmaxf(m_r[r], mx);
      float ps = 0.f;
#pragma unroll
      for (int j = 0; j < 4; ++j) {
        float p = __expf(sv[j][r] - mnew);
        bf16 pb = __float2bfloat16(p);
        Ps[w][(quad * 4 + r) * PSS + j * 16 + l16] = *reinterpret_cast<short*>(&pb);
        ps += p;
      }
      alpha[r] = __expf(m_r[r] - mnew);  // mnew uniform across group -> alpha uniform
      l_r[r] = l_r[r] * alpha[r] + ps;
      m_r[r] = mnew;
    }
    // rescale O
#pragma unroll
    for (int dj = 0; dj < 5; ++dj)
#pragma unroll
      for (int r = 0; r < 4; ++r) o[dj][r] *= alpha[r];
    // PV: O += P[16x64] @ Vt^T (Ps write->read same wave: compiler waits lgkmcnt)
#pragma unroll
    for (int st = 0; st < 2; ++st) {
      v8s ap = *reinterpret_cast<const v8s*>(&Ps[w][l16 * PSS + st * 32 + quad * 8]);
#pragma unroll
      for (int dj = 0; dj < 5; ++dj) {
        v8s bv_ = *reinterpret_cast<const v8s*>(&Vt[(dj * 16 + l16) * VTS + st * 32 + quad * 8]);
        o[dj] = __builtin_amdgcn_mfma_f32_16x16x32_bf16(ap, bv_, o[dj], 0, 0, 0);
      }
    }
  }
  // final l reduce across the 16-lane group, then write out (in-place over q)
  float linv[4];
#pragma unroll
  for (int r = 0; r < 4; ++r) {
    float lt = l_r[r];
#pragma unroll
    for (int o2 = 1; o2 < 16; o2 <<= 1) lt += __shfl_xor(lt, o2);
    linv[r] = (lt > 0.f) ? 1.f / lt : 0.f;
  }
#pragma unroll
  for (int dj = 0; dj < 5; ++dj) {
    int d = dj * 16 + l16;
    if (d >= Dn) continue;
#pragma unroll
    for (int r = 0; r < 4; ++r) {
      int qg = qt * ATQ + w * 16 + quad * 4 + r;
      if (qg < Nn)
        q[((size_t)(b * Nn + qg)) * Cn + h * Dn + d] = __float2bfloat16(o[dj][r] * linv[r]);
    }
  }
}

// -------- Decision path (fp64 — it is what makes ToMe match np) --------
__global__ __launch_bounds__(128) void wkavg_kernel(const float* __restrict__ wk,
                                                    const float* __restrict__ bk,
                                                    double* __restrict__ wka,
                                                    double* __restrict__ bka) {
  int c = blockIdx.x;
  int d = threadIdx.x;
  if (d < Dn) {
    double s = 0.0;
    for (int h = 0; h < Hn; ++h) s += (double)wk[(size_t)c * Cn + h * Dn + d];
    wka[(size_t)c * Dn + d] = s / Hn;
    if (c == 0) {
      double t = 0.0;
      for (int h = 0; h < Hn; ++h) t += (double)bk[h * Dn + d];
      bka[d] = t / Hn;
    }
  }
}

// Tiled fp64 GEMM (split-K): kpart[sk][row][d] = sum_{c in chunk sk} LN(x)[row][c]*wka[c][d]
constexpr int MT_ROWS = 64;
constexpr int MT_KT = 32;
constexpr int MT_SK = 3;
constexpr int MT_KC = Cn / MT_SK;  // 384
__global__ __launch_bounds__(256) void metric_gemm_kernel(const float* __restrict__ x,
                                                          const double* __restrict__ sd,
                                                          const float* __restrict__ g,
                                                          const float* __restrict__ b,
                                                          const double* __restrict__ wka,
                                                          double* __restrict__ kpart,
                                                          int rows) {
  int row0 = blockIdx.x * MT_ROWS;
  int k0base = blockIdx.y * MT_KC;
  __shared__ double As[MT_ROWS][MT_KT + 1];
  __shared__ double Ws[MT_KT][Dn];
  __shared__ double smean[MT_ROWS], srstd[MT_ROWS];
  int tid = threadIdx.x;
  int rg = tid >> 3;      // 0..31
  int dg = tid & 7;       // 0..7
  int d0 = dg * 9;
  if (tid < MT_ROWS) {
    int r = row0 + tid;
    smean[tid] = (r < rows) ? sd[2 * r] : 0.0;
    srstd[tid] = (r < rows) ? sd[2 * r + 1] : 0.0;
  }
  double acc0[9], acc1[9];
#pragma unroll
  for (int j = 0; j < 9; ++j) { acc0[j] = 0.0; acc1[j] = 0.0; }
  __syncthreads();
  for (int kt = 0; kt < MT_KC; kt += MT_KT) {
    int k0 = k0base + kt;
    __syncthreads();  // previous tile's reads complete
#pragma unroll
    for (int i = 0; i < 8; ++i) {
      int idx = tid + i * 256;
      int c = idx & 31, r = idx >> 5;
      int gr = row0 + r;
      double a = 0.0;
      if (gr < rows) {
        double xv = (double)x[(size_t)gr * Cn + k0 + c];
        a = (xv - smean[r]) * srstd[r] * (double)g[k0 + c] + (double)b[k0 + c];
      }
      As[r][c] = a;
    }
#pragma unroll
    for (int i = 0; i < 9; ++i) {
      int idx = tid + i * 256;
      int c = idx / Dn, d = idx % Dn;
      Ws[c][d] = wka[(size_t)(k0 + c) * Dn + d];
    }
    __syncthreads();
#pragma unroll 2
    for (int c = 0; c < MT_KT; ++c) {
      double a0 = As[rg * 2][c], a1 = As[rg * 2 + 1][c];
#pragma unroll
      for (int j = 0; j < 9; ++j) {
        double wv = Ws[c][d0 + j];
        acc0[j] += a0 * wv;
        acc1[j] += a1 * wv;
      }
    }
  }
  size_t base = (size_t)blockIdx.y * rows;
  int r0g = row0 + rg * 2;
#pragma unroll
  for (int j = 0; j < 9; ++j) {
    if (r0g < rows) kpart[(base + r0g) * Dn + d0 + j] = acc0[j];
    if (r0g + 1 < rows) kpart[(base + r0g + 1) * Dn + d0 + j] = acc1[j];
  }
}

// Combine split-K partials + bias, L2-normalize (same epilogue semantics as old metric_d)
__global__ __launch_bounds__(128) void metric_norm_kernel(const double* __restrict__ kpart,
                                                          const double* __restrict__ bka,
                                                          double* __restrict__ mn,
                                                          int rows) {
  int row = blockIdx.x;
  __shared__ double red[Dn];
  __shared__ double nrm;
  int d = threadIdx.x;
  double v = 0.0;
  if (d < Dn) {
    v = kpart[(size_t)row * Dn + d]
      + kpart[((size_t)rows + row) * Dn + d]
      + kpart[((size_t)2 * rows + row) * Dn + d]
      + bka[d];
    red[d] = v * v;
  }
  __syncthreads();
  if (threadIdx.x == 0) {
    double t = 0.0;
    for (int i = 0; i < Dn; ++i) t += red[i];
    nrm = 1.0 / sqrt(t > 0.0 ? t : 1e-300);
  }
  __syncthreads();
  if (d < Dn) mn[(size_t)row * Dn + d] = v * nrm;
}

__global__ __launch_bounds__(128) void tome_score_kernel(const double* __restrict__ mn,
                                                         double* __restrict__ nmax,
                                                         int* __restrict__ nidx) {
  int blk = blockIdx.x;
  int i = blk % NAn;
  int b = blk / NAn;
  __shared__ double av[Dn];
  __shared__ double sv[128];
  __shared__ int si[128];
  int tid = threadIdx.x;
  if (tid < Dn) av[tid] = mn[((size_t)(b * Nn) + 2 * i) * Dn + tid];
  __syncthreads();
  double best = -1e300;
  int bi = 0;
  for (int c2 = tid; c2 < NBn; c2 += 128) {
    const double* bv = mn + ((size_t)(b * Nn) + 2 * c2 + 1) * Dn;
    double s = 0.0;
#pragma unroll 8
    for (int dd = 0; dd < Dn; ++dd) s += av[dd] * bv[dd];
    if (s > best) { best = s; bi = c2; }  // strict > keeps first occurrence
  }
  sv[tid] = best;
  si[tid] = bi;
  __syncthreads();
  if (tid == 0) {
    double bb = sv[0];
    int ii = si[0];
    for (int t2 = 1; t2 < 128; ++t2) {
      if (sv[t2] > bb || (sv[t2] == bb && si[t2] < ii)) { bb = sv[t2]; ii = si[t2]; }
    }
    nmax[b * NAn + i] = bb;
    nidx[b * NAn + i] = clampi(ii, 0, NBn - 1);
  }
}

__global__ __launch_bounds__(512) void tome_sort_kernel(const double* __restrict__ nmax,
                                                        const int* __restrict__ nidx,
                                                        int* __restrict__ unm,
                                                        int* __restrict__ srcI,
                                                        int* __restrict__ dstI,
                                                        float* __restrict__ cnt) {
  int b = blockIdx.x;
  __shared__ double v[NAn];
  __shared__ int eidx[NAn];
  __shared__ int dsts[Rn];
  int tid = threadIdx.x;
  for (int i = tid; i < NAn; i += blockDim.x) {
    v[i] = nmax[b * NAn + i];
    eidx[i] = i;  // defensive init
  }
  __syncthreads();
  for (int i = tid; i < NAn; i += blockDim.x) {
    double vi = v[i];
    int rank = 0;
    for (int j = 0; j < NAn; ++j) {
      double vj = v[j];
      rank += (vj > vi) || (vj == vi && j < i);  // stable descending
    }
    eidx[clampi(rank, 0, NAn - 1)] = i;
  }
  __syncthreads();
  for (int r2 = tid; r2 < NAn; r2 += blockDim.x) {
    if (r2 >= Rn) unm[(size_t)b * UNMn + (r2 - Rn)] = clampi(eidx[r2], 0, NAn - 1);
  }
  if (tid < Rn) {
    int s = clampi(eidx[tid], 0, NAn - 1);
    srcI[b * Rn + tid] = s;
    int dd = clampi(nidx[b * NAn + s], 0, NBn - 1);
    dsts[tid] = dd;
    dstI[b * Rn + tid] = dd;
  }
  for (int j = tid; j < NBn; j += blockDim.x) cnt[(size_t)b * NBn + j] = 1.f;
  __syncthreads();
  if (tid == 0) {
    for (int r2 = 0; r2 < Rn; ++r2) cnt[(size_t)b * NBn + dsts[r2]] += 1.f;
  }
}

// -------- ToMe merge (fp32): [B,729,C] -> [B,706,C] --------
__global__ __launch_bounds__(256) void tome_merge_kernel(const float* __restrict__ h,
                                                         const int* __restrict__ unm,
                                                         const int* __restrict__ srcI,
                                                         const int* __restrict__ dstI,
                                                         const float* __restrict__ cnt,
                                                         float* __restrict__ mg) {
  int blk = blockIdx.x;
  int t = blk % NMn;
  int b = blk / NMn;
  __shared__ int s_src[Rn], s_dst[Rn];
  if (threadIdx.x < Rn) {
    s_src[threadIdx.x] = clampi(srcI[b * Rn + threadIdx.x], 0, NAn - 1);
    s_dst[threadIdx.x] = clampi(dstI[b * Rn + threadIdx.x], 0, NBn - 1);
  }
  __syncthreads();
  if (t < UNMn) {
    int tok = clampi(2 * clampi(unm[(size_t)b * UNMn + t], 0, NAn - 1), 0, Nn - 1);
    for (int c = threadIdx.x; c < Cn; c += 256)
      mg[((size_t)(b * NMn + t)) * Cn + c] = h[((size_t)(b * Nn + tok)) * Cn + c];
  } else {
    int j = t - UNMn;
    int tok = 2 * j + 1;
    float inv = 1.f / cnt[b * NBn + j];
    for (int c = threadIdx.x; c < Cn; c += 256) {
      float vsum = h[((size_t)(b * Nn + tok)) * Cn + c];
      for (int r2 = 0; r2 < Rn; ++r2)
        if (s_dst[r2] == j) vsum += h[((size_t)(b * Nn + 2 * s_src[r2])) * Cn + c];
      mg[((size_t)(b * NMn + t)) * Cn + c] = vsum * inv;
    }
  }
}

inline int cdiv(int a, int b) { return (a + b - 1) / b; }

}  // namespace

extern "C" void kernel_launch(void* const* d_in, const int* in_sizes, int n_in,
                              void* d_out, int out_size, void* d_ws, size_t ws_size,
                              hipStream_t stream) {
  const float* hidden = (const float*)d_in[0];
  const float* mask   = (const float*)d_in[1];
  const float* wq = (const float*)d_in[2];
  const float* bq = (const float*)d_in[3];
  const float* wk = (const float*)d_in[4];
  const float* bk = (const float*)d_in[5];
  const float* wv = (const float*)d_in[6];
  const float* bv = (const float*)d_in[7];
  const float* wo = (const float*)d_in[8];
  const float* bo = (const float*)d_in[9];
  const float* ln1w = (const float*)d_in[10];
  const float* ln1b = (const float*)d_in[11];
  const float* ln2w = (const float*)d_in[12];
  const float* ln2b = (const float*)d_in[13];
  const float* fc1w = (const float*)d_in[14];
  const float* fc1b = (const float*)d_in[15];
  const float* fc2w = (const float*)d_in[16];
  const float* fc2b = (const float*)d_in[17];
  float* out = (float*)d_out;
  (void)in_sizes; (void)n_in; (void)out_size;

  char* ws = (char*)d_ws;
  size_t off = 0;
  auto alloc = [&](size_t nbytes) -> void* {
    void* p = ws + off;
    off += (nbytes + 255) & ~(size_t)255;
    return p;
  };
  int rows = Bn * Nn;    // 5832
  int mrows = Bn * NMn;  // 5648
  size_t bnc = (size_t)rows * Cn;
  // QKV weights as ONE contiguous [3456][1152] buffer (fused GEMM)
  bf16* wqkvT = (bf16*)alloc((size_t)3 * Cn * Cn * 2);
  bf16* wqT = wqkvT;
  bf16* wkT = wqkvT + (size_t)Cn * Cn;
  bf16* wvT = wqkvT + (size_t)2 * Cn * Cn;
  bf16* woT = (bf16*)alloc((size_t)Cn * Cn * 2);
  bf16* fc1T = (bf16*)alloc((size_t)Fn * Cn * 2);
  bf16* fc2T = (bf16*)alloc((size_t)Cn * Fn * 2);
  bf16* xlnB = (bf16*)alloc(bnc * 2);             // LN1 out; later overlaid by mg (with qb)
  bf16* qb = (bf16*)alloc(bnc * 2);               // q -> attn-out (in-place)
  bf16* kb = (bf16*)alloc(bnc * 2);               // k; later overlaid by hbuf (with vb)
  bf16* vb = (bf16*)alloc(bnc * 2);               // v
  bf16* h2B = (bf16*)alloc((size_t)mrows * Cn * 2);
  double* mnD = (double*)alloc((size_t)rows * Dn * 8);
  double* wkavgD = (double*)alloc((size_t)Cn * Dn * 8);
  double* bkavgD = (double*)alloc((size_t)Dn * 8);
  float* stats1f = (float*)alloc((size_t)rows * 2 * 4);
  double* stats1d = (double*)alloc((size_t)rows * 2 * 8);
  float* stats2f = (float*)alloc((size_t)mrows * 2 * 4);
  double* nmaxD = (double*)alloc((size_t)Bn * NAn * 8);
  int* nidx = (int*)alloc((size_t)Bn * NAn * 4);
  int* unm  = (int*)alloc((size_t)Bn * UNMn * 4);
  int* srcI = (int*)alloc((size_t)Bn * Rn * 4);
  int* dstI = (int*)alloc((size_t)Bn * Rn * 4);
  float* cnt = (float*)alloc((size_t)Bn * NBn * 4);
  float* bqkv = (float*)alloc((size_t)3 * Cn * 4); // [SCALE*bq | bk | bv]
  // ffnB takes the REMAINING workspace (placed last).
  bf16* ffnB = (bf16*)(ws + off);
  size_t remain = (ws_size > off) ? (ws_size - off) : 0;
  size_t fullB = (size_t)mrows * Fn * 2;
  int CHUNK = (remain >= fullB) ? mrows : 2824;
  float* hbuf = (float*)kb;   // overlays kb+vb (dead after attn)
  float* mg   = (float*)xlnB; // overlays xlnB+qb (dead after QKV / wo-gemm)
  bf16* vtG   = ffnB;         // overlays ffnB (15.7MB; ffnB first written in step 9)
  double* kpartD = (double*)ffnB;  // overlays ffnB too (10.1MB; dead before vtG is written)

  // 0. Weight transpose+convert to bf16 [N][K]; wq gets SCALE folded in
  wconv_kernel<<<dim3(cdiv(Cn, 32), cdiv(Cn, 32)), 256, 0, stream>>>(wq, wqT, Cn, Cn, SCALEf);
  wconv_kernel<<<dim3(cdiv(Cn, 32), cdiv(Cn, 32)), 256, 0, stream>>>(wk, wkT, Cn, Cn, 1.f);
  wconv_kernel<<<dim3(cdiv(Cn, 32), cdiv(Cn, 32)), 256, 0, stream>>>(wv, wvT, Cn, Cn, 1.f);
  wconv_kernel<<<dim3(cdiv(Cn, 32), cdiv(Cn, 32)), 256, 0, stream>>>(wo, woT, Cn, Cn, 1.f);
  wconv_kernel<<<dim3(cdiv(Fn, 32), cdiv(Cn, 32)), 256, 0, stream>>>(fc1w, fc1T, Cn, Fn, 1.f);
  wconv_kernel<<<dim3(cdiv(Cn, 32), cdiv(Fn, 32)), 256, 0, stream>>>(fc2w, fc2T, Fn, Cn, 1.f);
  vscale_kernel<<<cdiv(Cn, 256), 256, 0, stream>>>(bq, bqkv, Cn, SCALEf);
  vscale_kernel<<<cdiv(Cn, 256), 256, 0, stream>>>(bk, bqkv + Cn, Cn, 1.f);
  vscale_kernel<<<cdiv(Cn, 256), 256, 0, stream>>>(bv, bqkv + 2 * Cn, Cn, 1.f);

  // 1. LN1 stats (fp32 + fp64)
  ln_stats_kernel<<<rows, 256, 0, stream>>>(hidden, stats1f, stats1d, rows);

  // 2. Decision path, all fp64 (split-K tiled GEMM + normalize)
  wkavg_kernel<<<Cn, 128, 0, stream>>>(wk, bk, wkavgD, bkavgD);
  metric_gemm_kernel<<<dim3(cdiv(rows, MT_ROWS), MT_SK), 256, 0, stream>>>(
      hidden, stats1d, ln1w, ln1b, wkavgD, kpartD, rows);
  metric_norm_kernel<<<rows, 128, 0, stream>>>(kpartD, bkavgD, mnD, rows);
  tome_score_kernel<<<Bn * NAn, 128, 0, stream>>>(mnD, nmaxD, nidx);
  tome_sort_kernel<<<Bn, 512, 0, stream>>>(nmaxD, nidx, unm, srcI, dstI, cnt);

  // 3. LN1 apply -> bf16
  ln_apply_kernel<<<rows, 256, 0, stream>>>(hidden, stats1f, ln1w, ln1b, xlnB);

  // 4. Fused QKV projection: one GEMM vs [3456][1152], epilogue routes to qb/kb/vb
  {
    int nx = cdiv(3 * Cn, 64), ny = cdiv(rows, 128);
    mfma_gemm<bf16, 128, 64><<<nx * ny, 256, 0, stream>>>(xlnB, wqkvT, bqkv, nullptr,
                                                          qb, kb, vb, rows, 3 * Cn, Cn, 0);
  }

  // 4.5 One-shot V transpose into padded [b,h,80,768] layout
  vtrans_kernel<<<Bn * Hn * 12, 256, 0, stream>>>(vb, vtG);

  // 5. MFMA flash attention (in-place over q); T14 prefetch, linear block decode
  attn_mfma_kernel<<<Bn * Hn * NQT2, 256, 0, stream>>>(qb, kb, vtG, mask);

  // 6. Out-proj + residual(hidden) -> hbuf fp32 (overlays kb+vb)
  {
    int nx = cdiv(Cn, 64), ny = cdiv(rows, 128);
    mfma_gemm<float, 128, 64><<<nx * ny, 256, 0, stream>>>(qb, woT, bo, hidden,
                                                           hbuf, nullptr, nullptr,
                                                           rows, Cn, Cn, 0);
  }

  // 7. ToMe merge -> mg fp32 (overlays xlnB+qb)
  tome_merge_kernel<<<Bn * NMn, 256, 0, stream>>>(hbuf, unm, srcI, dstI, cnt, mg);

  // 8. LN2 stats + apply -> h2B bf16
  ln_stats_kernel<<<mrows, 256, 0, stream>>>(mg, stats2f, (double*)nullptr, mrows);
  ln_apply_kernel<<<mrows, 256, 0, stream>>>(mg, stats2f, ln2w, ln2b, h2B);

  // 9. MLP (bf16 MFMA); fc1 128x128, fc2 128x64; single-shot if workspace allows
  for (int c0 = 0; c0 < mrows; c0 += CHUNK) {
    int m = (mrows - c0 < CHUNK) ? (mrows - c0) : CHUNK;
    {
      int nx = cdiv(Fn, 128), ny = cdiv(m, 128);
      mfma_gemm<bf16, 128, 128><<<nx * ny, 256, 0, stream>>>(h2B + (size_t)c0 * Cn, fc1T, fc1b,
                                                             nullptr, ffnB, nullptr, nullptr,
                                                             m, Fn, Cn, 1);
    }
    {
      int nx = cdiv(Cn, 64), ny = cdiv(m, 128);
      mfma_gemm<float, 128, 64><<<nx * ny, 256, 0, stream>>>(ffnB, fc2T, fc2b,
                                                             mg + (size_t)c0 * Cn,
                                                             out + (size_t)c0 * Cn,
                                                             nullptr, nullptr,
                                                             m, Cn, Fn, 0);
    }
  }
}

// Round 12
// 990.273 us; speedup vs baseline: 1.1253x; 1.1253x over previous
//
#include <hip/hip_runtime.h>
#include <hip/hip_bf16.h>
#include <math.h>

namespace {

constexpr int Bn = 8;
constexpr int Nn = 729;
constexpr int Cn = 1152;
constexpr int Hn = 16;
constexpr int Dn = 72;
constexpr int Fn = 4304;
constexpr int Rn = 23;
constexpr int NAn = 365;              // even tokens (src half)
constexpr int NBn = 364;              // odd tokens (dst half)
constexpr int NMn = 706;              // N - R merged tokens
constexpr int UNMn = NAn - Rn;        // 342 unmerged
constexpr float EPSf = 1e-6f;
constexpr float SCALEf = 0.11785113019775793f;  // 72^-0.5

using bf16 = __hip_bfloat16;
typedef short v8s __attribute__((ext_vector_type(8)));
typedef float v4f __attribute__((ext_vector_type(4)));

__device__ __forceinline__ float toF(bf16 v) { return __bfloat162float(v); }
__device__ __forceinline__ void stF(float* p, float v) { *p = v; }
__device__ __forceinline__ void stF(bf16* p, float v) { *p = __float2bfloat16(v); }

__device__ __forceinline__ float geluf(float x) {
  float x3 = x * x * x;
  return 0.5f * x * (1.f + tanhf(0.7978845608028654f * (x + 0.044715f * x3)));
}

__device__ __forceinline__ int clampi(int v, int lo, int hi) {
  return v < lo ? lo : (v > hi ? hi : v);
}

// async global -> LDS, 16B per lane; LDS dest is wave-uniform base + lane*16
__device__ __forceinline__ void gl_lds16(const bf16* __restrict__ g, short* l) {
  __builtin_amdgcn_global_load_lds(
      (const __attribute__((address_space(1))) void*)g,
      (__attribute__((address_space(3))) void*)l, 16, 0, 0);
}

// -------- LN stats: one block per row; fp32 (value path) + optional fp64 (decision path) --------
__global__ __launch_bounds__(256) void ln_stats_kernel(const float* __restrict__ x,
                                                       float* __restrict__ sf,
                                                       double* __restrict__ sd,
                                                       int rows) {
  int row = blockIdx.x;
  if (row >= rows) return;
  const float* xr = x + (size_t)row * Cn;
  double s = 0.0, s2 = 0.0;
  for (int c = threadIdx.x; c < Cn; c += 256) {
    double v = (double)xr[c];
    s += v; s2 += v * v;
  }
  __shared__ double sh[8];
#pragma unroll
  for (int o = 32; o > 0; o >>= 1) { s += __shfl_down(s, o); s2 += __shfl_down(s2, o); }
  int w = threadIdx.x >> 6;
  if ((threadIdx.x & 63) == 0) { sh[w] = s; sh[4 + w] = s2; }
  __syncthreads();
  if (threadIdx.x == 0) {
    double ts = sh[0] + sh[1] + sh[2] + sh[3];
    double ts2 = sh[4] + sh[5] + sh[6] + sh[7];
    double mean = ts / Cn;
    double var = ts2 / Cn - mean * mean;
    double rstd = 1.0 / sqrt(var + (double)EPSf);
    sf[2 * row] = (float)mean;
    sf[2 * row + 1] = (float)rstd;
    if (sd) { sd[2 * row] = mean; sd[2 * row + 1] = rstd; }
  }
}

// -------- LN apply -> bf16 tensor --------
__global__ __launch_bounds__(256) void ln_apply_kernel(const float* __restrict__ x,
                                                       const float* __restrict__ stats,
                                                       const float* __restrict__ g,
                                                       const float* __restrict__ b,
                                                       bf16* __restrict__ y) {
  int row = blockIdx.x;
  float mean = stats[2 * row], rstd = stats[2 * row + 1];
  const float* xr = x + (size_t)row * Cn;
  bf16* yr = y + (size_t)row * Cn;
  for (int c = threadIdx.x; c < Cn; c += 256)
    yr[c] = __float2bfloat16((xr[c] - mean) * rstd * g[c] + b[c]);
}

// -------- Weight transpose+convert: W[K][N] fp32 -> Wt[N][K] bf16 (x scale) --------
__global__ __launch_bounds__(256) void wconv_kernel(const float* __restrict__ W,
                                                    bf16* __restrict__ Wt,
                                                    int K, int N, float scale) {
  __shared__ float tile[32][33];
  int kt = blockIdx.y * 32, nt = blockIdx.x * 32;
  int tx = threadIdx.x & 31, ty = threadIdx.x >> 5;  // ty 0..7
#pragma unroll
  for (int yy = 0; yy < 4; ++yy) {
    int k = kt + ty * 4 + yy, n = nt + tx;
    tile[ty * 4 + yy][tx] = (k < K && n < N) ? W[(size_t)k * N + n] : 0.f;
  }
  __syncthreads();
#pragma unroll
  for (int yy = 0; yy < 4; ++yy) {
    int n = nt + ty * 4 + yy, k = kt + tx;
    if (n < N && k < K) Wt[(size_t)n * K + k] = __float2bfloat16(tile[tx][ty * 4 + yy] * scale);
  }
}

// -------- scale/copy a float vector --------
__global__ __launch_bounds__(256) void vscale_kernel(const float* __restrict__ in,
                                                     float* __restrict__ out, int n, float s) {
  int i = blockIdx.x * 256 + threadIdx.x;
  if (i < n) out[i] = in[i] * s;
}

// -------- MFMA GEMM (tile-templated, swizzled 1D grid, BK=64, XOR-swizzled LDS) ----------------
// Round-10 measured config (best total 1048us; GEMMs out of top-5): BK=64 halves barriers vs
// BK=32; LDS rows are 128B so fragment reads XOR-swizzle the chunk index per rule #21
// (both-sides-or-neither with global_load_lds): physical chunk = logical ^ (row&7);
//  - interior: pre-swizzle per-lane GLOBAL source (lane i loads logical chunk (i&7)^(i>>3));
//  - fallback: thread at linear LDS pos (r, pc) loads global logical chunk pc^(r&7);
//  - reads: ((ks2*4+quad)^(l16&7)) -> conflict-free (bank conflicts 4.2e7 -> GEMMs left top-5).
// Tile order: m204 bijective XCD-chunking + GROUP_M=6 serpentine (FETCH 305->125MB).
// Optional 3-way column-split epilogue (QKV fusion).
template <typename OT, int BT>
__global__ __launch_bounds__(256) void mfma_gemm(const bf16* __restrict__ A,
                                                 const bf16* __restrict__ Wt,
                                                 const float* __restrict__ bias,
                                                 const float* __restrict__ resid,
                                                 OT* __restrict__ Cout,
                                                 OT* __restrict__ C2,
                                                 OT* __restrict__ C3,
                                                 int M, int N, int K, int act) {
  constexpr int FR = BT / 32;       // frags per wave per dim
  constexpr int ISS = BT / 32;      // gl_lds issues per array per wave (8 rows each)
  constexpr int PIT = BT / 32;      // fallback staging iterations per array
  constexpr int GM = 6;             // row-panel group (L2 working set)
  __align__(16) __shared__ short As[BT * 64];
  __align__(16) __shared__ short Bs[BT * 64];
  // ---- tile decode ----
  int nx = (N + BT - 1) / BT, ny = (M + BT - 1) / BT;
  int nwg = nx * ny;                // == gridDim.x
  int blk = blockIdx.x;
  int q8 = nwg >> 3, r8 = nwg & 7;
  int xcd = blk & 7, slot = blk >> 3;
  int wgid = (xcd < r8 ? xcd * (q8 + 1) : r8 * (q8 + 1) + (xcd - r8) * q8) + slot;
  int npg = GM * nx;
  int gid = wgid / npg;
  int rem = wgid - gid * npg;
  int m0 = gid * GM;
  int gsz = ny - m0; if (gsz > GM) gsz = GM;
  int by = m0 + rem % gsz;
  int bx = rem / gsz;
  int bm = by * BT, bn = bx * BT;
  // ---- per-thread ids ----
  int tid = threadIdx.x;
  int lane = tid & 63, w = tid >> 6;
  int wm = w >> 1, wn = w & 1;
  int l16 = lane & 15, quad = lane >> 4;
  int lr8 = lane >> 3;
  int lc8s = (((lane & 7) ^ (lane >> 3)) * 8);   // swizzled global chunk for gl_lds staging
  bool interior = (bm + BT <= M) && (bn + BT <= N);
  v4f acc[FR][FR];
#pragma unroll
  for (int i = 0; i < FR; ++i)
#pragma unroll
    for (int j = 0; j < FR; ++j) acc[i][j] = (v4f){0.f, 0.f, 0.f, 0.f};
  int ksteps = (K + 63) / 64;
  for (int ks = 0; ks < ksteps; ++ks) {
    int k0 = ks * 64;
    __syncthreads();
    if (interior && (k0 + 64 <= K)) {
#pragma unroll
      for (int h2 = 0; h2 < ISS; ++h2) {
        int rb = w * (BT / 4) + h2 * 8;   // multiple of 8 -> row&7 == lane>>3
        int r = rb + lr8;
        gl_lds16(A + (size_t)(bm + r) * K + k0 + lc8s, &As[rb * 64]);
        gl_lds16(Wt + (size_t)(bn + r) * K + k0 + lc8s, &Bs[rb * 64]);
      }
    } else {
#pragma unroll
      for (int p = 0; p < PIT; ++p) {
        int idx = tid + p * 256;
        int r = idx >> 3, pc = idx & 7;
        int lc = pc ^ (r & 7);            // logical chunk stored at physical pc
        int cg = lc * 8;
        int4 za = {0, 0, 0, 0}, zb = {0, 0, 0, 0};
        if (k0 + cg < K) {  // K%8==0 so group-granular guard is exact
          if (bm + r < M) za = *reinterpret_cast<const int4*>(A + (size_t)(bm + r) * K + k0 + cg);
          if (bn + r < N) zb = *reinterpret_cast<const int4*>(Wt + (size_t)(bn + r) * K + k0 + cg);
        }
        *reinterpret_cast<int4*>(&As[r * 64 + pc * 8]) = za;
        *reinterpret_cast<int4*>(&Bs[r * 64 + pc * 8]) = zb;
      }
    }
    __syncthreads();
#pragma unroll
    for (int ks2 = 0; ks2 < 2; ++ks2) {
      int pcr = ((ks2 * 4 + quad) ^ (l16 & 7)) * 8;  // swizzled read chunk (row&7 == l16&7)
      v8s af[FR], bfr[FR];
#pragma unroll
      for (int i = 0; i < FR; ++i)
        af[i] = *reinterpret_cast<const v8s*>(
            &As[(wm * (BT / 2) + i * 16 + l16) * 64 + pcr]);
#pragma unroll
      for (int j = 0; j < FR; ++j)
        bfr[j] = *reinterpret_cast<const v8s*>(
            &Bs[(wn * (BT / 2) + j * 16 + l16) * 64 + pcr]);
#pragma unroll
      for (int i = 0; i < FR; ++i)
#pragma unroll
        for (int j = 0; j < FR; ++j)
          acc[i][j] = __builtin_amdgcn_mfma_f32_16x16x32_bf16(af[i], bfr[j], acc[i][j], 0, 0, 0);
    }
  }
  int w3 = C2 ? (N / 3) : 0;
#pragma unroll
  for (int i = 0; i < FR; ++i) {
#pragma unroll
    for (int j = 0; j < FR; ++j) {
#pragma unroll
      for (int r = 0; r < 4; ++r) {
        int row = bm + wm * (BT / 2) + i * 16 + quad * 4 + r;
        int col = bn + wn * (BT / 2) + j * 16 + l16;
        if (row < M && col < N) {
          float v = acc[i][j][r] + bias[col];
          if (act) v = geluf(v);
          if (resid) v += resid[(size_t)row * N + col];
          if (C2) {
            int seg = col / w3, c2 = col - seg * w3;
            OT* d = (seg == 0) ? Cout : (seg == 1 ? C2 : C3);
            stF(&d[(size_t)row * w3 + c2], v);
          } else {
            stF(&Cout[(size_t)row * N + col], v);
          }
        }
      }
    }
  }
}

// -------- V transpose (one-shot): vb[b,n,h*D+d] -> vt[(b*H+h)*80 + d][768 keys] --------
// d-rows padded 72->80 (zeros), keys padded 729->768 (zeros). Padded-LDS tile transpose.
constexpr int NKP = 768;  // padded key count (12 tiles x 64)
__global__ __launch_bounds__(256) void vtrans_kernel(const bf16* __restrict__ v,
                                                     bf16* __restrict__ vt) {
  int kb = blockIdx.x % 12;   // 64-key block
  int bh = blockIdx.x / 12;
  int h = bh % Hn, b = bh / Hn;
  __shared__ short Ts[64][73];  // +1 short pad: stride 146B -> ~2-way on column reads
  int tid = threadIdx.x;
  // load 64 keys x 72 d (scalar, coalesced on d)
#pragma unroll
  for (int i = 0; i < 18; ++i) {
    int idx = tid + i * 256;  // < 4608
    int key = idx / 72, d = idx % 72;
    int kg = kb * 64 + key;
    bf16 val = (kg < Nn) ? v[((size_t)(b * Nn + kg)) * Cn + h * Dn + d] : bf16(0.f);
    Ts[key][d] = *reinterpret_cast<short*>(&val);
  }
  __syncthreads();
  // write 72 d-rows x 64 keys (scalar, coalesced on key)
#pragma unroll
  for (int i = 0; i < 18; ++i) {
    int idx = tid + i * 256;
    int d = idx / 64, key = idx % 64;
    vt[((size_t)bh * 80 + d) * NKP + kb * 64 + key] = *reinterpret_cast<bf16*>(&Ts[key][d]);
  }
  // zero pad rows d=72..79
  for (int i = tid; i < 8 * 64; i += 256) {
    int d = 72 + i / 64, key = i % 64;
    vt[((size_t)bh * 80 + d) * NKP + kb * 64 + key] = bf16(0.f);
  }
}

// -------- MFMA flash attention: one block = (b, h, 64-query tile); in-place over q --------
// EXACT round-4 body (measured 165us, VGPR 84, occ 33%, WRITE 14.5MB): linear decode,
// T14 reg-prefetch, __expf, fast-path mask, FULL-shfl softmax (ps reduced per tile; direct
// 1/l epilogue). Rounds 9-11's per-lane-l variants measured 183-207us (VGPR 88-92, occ 22%,
// WRITE 25-54MB) -> reverted to the measured-good body.
constexpr int ATQ = 64, ATK = 64;
constexpr int NQT2 = (Nn + ATQ - 1) / ATQ;  // 12
constexpr int NKT = 12;                     // 64-key tiles
constexpr int KSS = 104, VTS = 72, PSS = 72;

__device__ __forceinline__ void attn_load_tile(const bf16* __restrict__ k,
                                               const bf16* __restrict__ vt,
                                               int b, int bh, int h, int kt_, int tid,
                                               int4* kr, int4* vr) {
#pragma unroll
  for (int i = 0; i < 3; ++i) {
    int idx = tid + i * 256;
    int r = idx / 12, ch = idx % 12;
    int kg = kt_ + r;
    int4 z = {0, 0, 0, 0};
    if (ch < 9 && kg < Nn)
      z = *reinterpret_cast<const int4*>(k + ((size_t)(b * Nn + kg)) * Cn + h * Dn + ch * 8);
    kr[i] = z;
    if (idx < 640) {
      int d = idx >> 3, kc = idx & 7;
      vr[i] = *reinterpret_cast<const int4*>(vt + ((size_t)bh * 80 + d) * NKP + kt_ + kc * 8);
    }
  }
}

__global__ __launch_bounds__(256) void attn_mfma_kernel(bf16* q /* in: q, out: attn */,
                                                        const bf16* __restrict__ k,
                                                        const bf16* __restrict__ vt,
                                                        const float* __restrict__ mask) {
  int blk = blockIdx.x;
  int qt = blk % NQT2;
  int bh = blk / NQT2;
  int h = bh % Hn;
  int b = bh / Hn;
  __align__(16) __shared__ short Ks[ATK * KSS];
  __align__(16) __shared__ short Vt[80 * VTS];
  __align__(16) __shared__ short Ps[4][16 * PSS];
  int tid = threadIdx.x;
  int lane = tid & 63, w = tid >> 6;
  int l16 = lane & 15, quad = lane >> 4;

  // Q fragments straight to registers (each wave only ever needs its own 16 rows)
  v8s aq[3];
  int qg_l = qt * ATQ + w * 16 + l16;
  {
    const bf16* qrow = q + ((size_t)(b * Nn + (qg_l < Nn ? qg_l : 0))) * Cn + h * Dn;
#pragma unroll
    for (int ks = 0; ks < 3; ++ks) {
      bool valid = (qg_l < Nn) && (ks < 2 || quad == 0);  // ks=2: d=64..71 only for quad 0
      if (valid)
        aq[ks] = *reinterpret_cast<const v8s*>(qrow + ks * 32 + quad * 8);
      else
        aq[ks] = (v8s){0, 0, 0, 0, 0, 0, 0, 0};
    }
  }

  v4f o[5];
#pragma unroll
  for (int dj = 0; dj < 5; ++dj) o[dj] = (v4f){0.f, 0.f, 0.f, 0.f};
  float m_r[4] = {-INFINITY, -INFINITY, -INFINITY, -INFINITY};
  float l_r[4] = {0.f, 0.f, 0.f, 0.f};

  int4 kr[3], vr[3];
  attn_load_tile(k, vt, b, bh, h, 0, tid, kr, vr);

  for (int t = 0; t < NKT; ++t) {
    int kt2 = t * ATK;
    __syncthreads();  // previous tile's LDS reads complete
    // regs -> LDS (write-late half of T14 split)
#pragma unroll
    for (int i = 0; i < 3; ++i) {
      int idx = tid + i * 256;
      int r = idx / 12, ch = idx % 12;
      *reinterpret_cast<int4*>(&Ks[r * KSS + ch * 8]) = kr[i];
      if (idx < 640) {
        int d = idx >> 3, kc = idx & 7;
        *reinterpret_cast<int4*>(&Vt[d * VTS + kc * 8]) = vr[i];
      }
    }
    __syncthreads();
    // issue next tile's global loads early; latency hides under compute below
    if (t + 1 < NKT) attn_load_tile(k, vt, b, bh, h, kt2 + ATK, tid, kr, vr);

    // QK^T: S[16q x 64k] per wave, 12 MFMA (scores arrive pre-scaled)
    v4f sfr[4];
#pragma unroll
    for (int j = 0; j < 4; ++j) sfr[j] = (v4f){0.f, 0.f, 0.f, 0.f};
#pragma unroll
    for (int ks = 0; ks < 3; ++ks) {
#pragma unroll
      for (int j = 0; j < 4; ++j) {
        v8s bk_ = *reinterpret_cast<const v8s*>(&Ks[(j * 16 + l16) * KSS + ks * 32 + quad * 8]);
        sfr[j] = __builtin_amdgcn_mfma_f32_16x16x32_bf16(aq[ks], bk_, sfr[j], 0, 0, 0);
      }
    }
    // + mask (C layout: col=j*16+l16, row=quad*4+r); fast path for full tiles
    float sv[4][4];
    int qbase = qt * ATQ + w * 16 + quad * 4;
    bool tfull = (kt2 + ATK <= Nn);
#pragma unroll
    for (int r = 0; r < 4; ++r) {
      int qg = qbase + r;
      const float* mrow = mask + ((size_t)(b * Nn + (qg < Nn ? qg : 0))) * Nn;
      if (tfull && qg < Nn) {
#pragma unroll
        for (int j = 0; j < 4; ++j) sv[j][r] = sfr[j][r] + mrow[kt2 + j * 16 + l16];
      } else {
#pragma unroll
        for (int j = 0; j < 4; ++j) {
          int kg = kt2 + j * 16 + l16;
          sv[j][r] = (kg < Nn && qg < Nn) ? sfr[j][r] + mrow[kg] : -INFINITY;
        }
      }
    }
    // online softmax per row (reduce across 16 lanes of the quad-group)
    float alpha[4];
#pragma unroll
    for (int r = 0; r < 4; ++r) {
      float mx = fmaxf(fmaxf(sv[0][r], sv[1][r]), fmaxf(sv[2][r], sv[3][r]));
#pragma unroll
      for (int o2 = 1; o2 < 16; o2 <<= 1) mx = fmaxf(mx, __shfl_xor(mx, o2));
      float mnew = fmaxf(m_r[r], mx);
      float ps = 0.f;
#pragma unroll
      for (int j = 0; j < 4; ++j) {
        float p = __expf(sv[j][r] - mnew);
        bf16 pb = __float2bfloat16(p);
        Ps[w][(quad * 4 + r) * PSS + j * 16 + l16] = *reinterpret_cast<short*>(&pb);
        ps += p;
      }
#pragma unroll
      for (int o2 = 1; o2 < 16; o2 <<= 1) ps += __shfl_xor(ps, o2);
      alpha[r] = __expf(m_r[r] - mnew);
      l_r[r] = l_r[r] * alpha[r] + ps;
      m_r[r] = mnew;
    }
    // rescale O
#pragma unroll
    for (int dj = 0; dj < 5; ++dj)
#pragma unroll
      for (int r = 0; r < 4; ++r) o[dj][r] *= alpha[r];
    // PV: O += P[16x64] @ Vt^T (Ps write->read same wave: compiler waits lgkmcnt)
#pragma unroll
    for (int st = 0; st < 2; ++st) {
      v8s ap = *reinterpret_cast<const v8s*>(&Ps[w][l16 * PSS + st * 32 + quad * 8]);
#pragma unroll
      for (int dj = 0; dj < 5; ++dj) {
        v8s bv_ = *reinterpret_cast<const v8s*>(&Vt[(dj * 16 + l16) * VTS + st * 32 + quad * 8]);
        o[dj] = __builtin_amdgcn_mfma_f32_16x16x32_bf16(ap, bv_, o[dj], 0, 0, 0);
      }
    }
  }
  // write out (in-place over q)
  float linv[4];
#pragma unroll
  for (int r = 0; r < 4; ++r) linv[r] = (l_r[r] > 0.f) ? 1.f / l_r[r] : 0.f;
#pragma unroll
  for (int dj = 0; dj < 5; ++dj) {
    int d = dj * 16 + l16;
    if (d >= Dn) continue;
#pragma unroll
    for (int r = 0; r < 4; ++r) {
      int qg = qt * ATQ + w * 16 + quad * 4 + r;
      if (qg < Nn)
        q[((size_t)(b * Nn + qg)) * Cn + h * Dn + d] = __float2bfloat16(o[dj][r] * linv[r]);
    }
  }
}

// -------- Decision path (fp64 — it is what makes ToMe match np) --------
__global__ __launch_bounds__(128) void wkavg_kernel(const float* __restrict__ wk,
                                                    const float* __restrict__ bk,
                                                    double* __restrict__ wka,
                                                    double* __restrict__ bka) {
  int c = blockIdx.x;
  int d = threadIdx.x;
  if (d < Dn) {
    double s = 0.0;
    for (int h = 0; h < Hn; ++h) s += (double)wk[(size_t)c * Cn + h * Dn + d];
    wka[(size_t)c * Dn + d] = s / Hn;
    if (c == 0) {
      double t = 0.0;
      for (int h = 0; h < Hn; ++h) t += (double)bk[h * Dn + d];
      bka[d] = t / Hn;
    }
  }
}

// Tiled fp64 GEMM (split-K): kpart[sk][row][d] = sum_{c in chunk sk} LN(x)[row][c]*wka[c][d]
constexpr int MT_ROWS = 64;
constexpr int MT_KT = 32;
constexpr int MT_SK = 3;
constexpr int MT_KC = Cn / MT_SK;  // 384
__global__ __launch_bounds__(256) void metric_gemm_kernel(const float* __restrict__ x,
                                                          const double* __restrict__ sd,
                                                          const float* __restrict__ g,
                                                          const float* __restrict__ b,
                                                          const double* __restrict__ wka,
                                                          double* __restrict__ kpart,
                                                          int rows) {
  int row0 = blockIdx.x * MT_ROWS;
  int k0base = blockIdx.y * MT_KC;
  __shared__ double As[MT_ROWS][MT_KT + 1];
  __shared__ double Ws[MT_KT][Dn];
  __shared__ double smean[MT_ROWS], srstd[MT_ROWS];
  int tid = threadIdx.x;
  int rg = tid >> 3;      // 0..31
  int dg = tid & 7;       // 0..7
  int d0 = dg * 9;
  if (tid < MT_ROWS) {
    int r = row0 + tid;
    smean[tid] = (r < rows) ? sd[2 * r] : 0.0;
    srstd[tid] = (r < rows) ? sd[2 * r + 1] : 0.0;
  }
  double acc0[9], acc1[9];
#pragma unroll
  for (int j = 0; j < 9; ++j) { acc0[j] = 0.0; acc1[j] = 0.0; }
  __syncthreads();
  for (int kt = 0; kt < MT_KC; kt += MT_KT) {
    int k0 = k0base + kt;
    __syncthreads();  // previous tile's reads complete
#pragma unroll
    for (int i = 0; i < 8; ++i) {
      int idx = tid + i * 256;
      int c = idx & 31, r = idx >> 5;
      int gr = row0 + r;
      double a = 0.0;
      if (gr < rows) {
        double xv = (double)x[(size_t)gr * Cn + k0 + c];
        a = (xv - smean[r]) * srstd[r] * (double)g[k0 + c] + (double)b[k0 + c];
      }
      As[r][c] = a;
    }
#pragma unroll
    for (int i = 0; i < 9; ++i) {
      int idx = tid + i * 256;
      int c = idx / Dn, d = idx % Dn;
      Ws[c][d] = wka[(size_t)(k0 + c) * Dn + d];
    }
    __syncthreads();
#pragma unroll 2
    for (int c = 0; c < MT_KT; ++c) {
      double a0 = As[rg * 2][c], a1 = As[rg * 2 + 1][c];
#pragma unroll
      for (int j = 0; j < 9; ++j) {
        double wv = Ws[c][d0 + j];
        acc0[j] += a0 * wv;
        acc1[j] += a1 * wv;
      }
    }
  }
  size_t base = (size_t)blockIdx.y * rows;
  int r0g = row0 + rg * 2;
#pragma unroll
  for (int j = 0; j < 9; ++j) {
    if (r0g < rows) kpart[(base + r0g) * Dn + d0 + j] = acc0[j];
    if (r0g + 1 < rows) kpart[(base + r0g + 1) * Dn + d0 + j] = acc1[j];
  }
}

// Combine split-K partials + bias, L2-normalize (same epilogue semantics as old metric_d)
__global__ __launch_bounds__(128) void metric_norm_kernel(const double* __restrict__ kpart,
                                                          const double* __restrict__ bka,
                                                          double* __restrict__ mn,
                                                          int rows) {
  int row = blockIdx.x;
  __shared__ double red[Dn];
  __shared__ double nrm;
  int d = threadIdx.x;
  double v = 0.0;
  if (d < Dn) {
    v = kpart[(size_t)row * Dn + d]
      + kpart[((size_t)rows + row) * Dn + d]
      + kpart[((size_t)2 * rows + row) * Dn + d]
      + bka[d];
    red[d] = v * v;
  }
  __syncthreads();
  if (threadIdx.x == 0) {
    double t = 0.0;
    for (int i = 0; i < Dn; ++i) t += red[i];
    nrm = 1.0 / sqrt(t > 0.0 ? t : 1e-300);
  }
  __syncthreads();
  if (d < Dn) mn[(size_t)row * Dn + d] = v * nrm;
}

__global__ __launch_bounds__(128) void tome_score_kernel(const double* __restrict__ mn,
                                                         double* __restrict__ nmax,
                                                         int* __restrict__ nidx) {
  int blk = blockIdx.x;
  int i = blk % NAn;
  int b = blk / NAn;
  __shared__ double av[Dn];
  __shared__ double sv[128];
  __shared__ int si[128];
  int tid = threadIdx.x;
  if (tid < Dn) av[tid] = mn[((size_t)(b * Nn) + 2 * i) * Dn + tid];
  __syncthreads();
  double best = -1e300;
  int bi = 0;
  for (int c2 = tid; c2 < NBn; c2 += 128) {
    const double* bv = mn + ((size_t)(b * Nn) + 2 * c2 + 1) * Dn;
    double s = 0.0;
#pragma unroll 8
    for (int dd = 0; dd < Dn; ++dd) s += av[dd] * bv[dd];
    if (s > best) { best = s; bi = c2; }  // strict > keeps first occurrence
  }
  sv[tid] = best;
  si[tid] = bi;
  __syncthreads();
  if (tid == 0) {
    double bb = sv[0];
    int ii = si[0];
    for (int t2 = 1; t2 < 128; ++t2) {
      if (sv[t2] > bb || (sv[t2] == bb && si[t2] < ii)) { bb = sv[t2]; ii = si[t2]; }
    }
    nmax[b * NAn + i] = bb;
    nidx[b * NAn + i] = clampi(ii, 0, NBn - 1);
  }
}

__global__ __launch_bounds__(512) void tome_sort_kernel(const double* __restrict__ nmax,
                                                        const int* __restrict__ nidx,
                                                        int* __restrict__ unm,
                                                        int* __restrict__ srcI,
                                                        int* __restrict__ dstI,
                                                        float* __restrict__ cnt) {
  int b = blockIdx.x;
  __shared__ double v[NAn];
  __shared__ int eidx[NAn];
  __shared__ int dsts[Rn];
  int tid = threadIdx.x;
  for (int i = tid; i < NAn; i += blockDim.x) {
    v[i] = nmax[b * NAn + i];
    eidx[i] = i;  // defensive init
  }
  __syncthreads();
  for (int i = tid; i < NAn; i += blockDim.x) {
    double vi = v[i];
    int rank = 0;
    for (int j = 0; j < NAn; ++j) {
      double vj = v[j];
      rank += (vj > vi) || (vj == vi && j < i);  // stable descending
    }
    eidx[clampi(rank, 0, NAn - 1)] = i;
  }
  __syncthreads();
  for (int r2 = tid; r2 < NAn; r2 += blockDim.x) {
    if (r2 >= Rn) unm[(size_t)b * UNMn + (r2 - Rn)] = clampi(eidx[r2], 0, NAn - 1);
  }
  if (tid < Rn) {
    int s = clampi(eidx[tid], 0, NAn - 1);
    srcI[b * Rn + tid] = s;
    int dd = clampi(nidx[b * NAn + s], 0, NBn - 1);
    dsts[tid] = dd;
    dstI[b * Rn + tid] = dd;
  }
  for (int j = tid; j < NBn; j += blockDim.x) cnt[(size_t)b * NBn + j] = 1.f;
  __syncthreads();
  if (tid == 0) {
    for (int r2 = 0; r2 < Rn; ++r2) cnt[(size_t)b * NBn + dsts[r2]] += 1.f;
  }
}

// -------- ToMe merge (fp32): [B,729,C] -> [B,706,C] --------
__global__ __launch_bounds__(256) void tome_merge_kernel(const float* __restrict__ h,
                                                         const int* __restrict__ unm,
                                                         const int* __restrict__ srcI,
                                                         const int* __restrict__ dstI,
                                                         const float* __restrict__ cnt,
                                                         float* __restrict__ mg) {
  int blk = blockIdx.x;
  int t = blk % NMn;
  int b = blk / NMn;
  __shared__ int s_src[Rn], s_dst[Rn];
  if (threadIdx.x < Rn) {
    s_src[threadIdx.x] = clampi(srcI[b * Rn + threadIdx.x], 0, NAn - 1);
    s_dst[threadIdx.x] = clampi(dstI[b * Rn + threadIdx.x], 0, NBn - 1);
  }
  __syncthreads();
  if (t < UNMn) {
    int tok = clampi(2 * clampi(unm[(size_t)b * UNMn + t], 0, NAn - 1), 0, Nn - 1);
    for (int c = threadIdx.x; c < Cn; c += 256)
      mg[((size_t)(b * NMn + t)) * Cn + c] = h[((size_t)(b * Nn + tok)) * Cn + c];
  } else {
    int j = t - UNMn;
    int tok = 2 * j + 1;
    float inv = 1.f / cnt[b * NBn + j];
    for (int c = threadIdx.x; c < Cn; c += 256) {
      float vsum = h[((size_t)(b * Nn + tok)) * Cn + c];
      for (int r2 = 0; r2 < Rn; ++r2)
        if (s_dst[r2] == j) vsum += h[((size_t)(b * Nn + 2 * s_src[r2])) * Cn + c];
      mg[((size_t)(b * NMn + t)) * Cn + c] = vsum * inv;
    }
  }
}

inline int cdiv(int a, int b) { return (a + b - 1) / b; }

}  // namespace

extern "C" void kernel_launch(void* const* d_in, const int* in_sizes, int n_in,
                              void* d_out, int out_size, void* d_ws, size_t ws_size,
                              hipStream_t stream) {
  const float* hidden = (const float*)d_in[0];
  const float* mask   = (const float*)d_in[1];
  const float* wq = (const float*)d_in[2];
  const float* bq = (const float*)d_in[3];
  const float* wk = (const float*)d_in[4];
  const float* bk = (const float*)d_in[5];
  const float* wv = (const float*)d_in[6];
  const float* bv = (const float*)d_in[7];
  const float* wo = (const float*)d_in[8];
  const float* bo = (const float*)d_in[9];
  const float* ln1w = (const float*)d_in[10];
  const float* ln1b = (const float*)d_in[11];
  const float* ln2w = (const float*)d_in[12];
  const float* ln2b = (const float*)d_in[13];
  const float* fc1w = (const float*)d_in[14];
  const float* fc1b = (const float*)d_in[15];
  const float* fc2w = (const float*)d_in[16];
  const float* fc2b = (const float*)d_in[17];
  float* out = (float*)d_out;
  (void)in_sizes; (void)n_in; (void)out_size;

  char* ws = (char*)d_ws;
  size_t off = 0;
  auto alloc = [&](size_t nbytes) -> void* {
    void* p = ws + off;
    off += (nbytes + 255) & ~(size_t)255;
    return p;
  };
  int rows = Bn * Nn;    // 5832
  int mrows = Bn * NMn;  // 5648
  size_t bnc = (size_t)rows * Cn;
  // QKV weights as ONE contiguous [3456][1152] buffer (fused GEMM)
  bf16* wqkvT = (bf16*)alloc((size_t)3 * Cn * Cn * 2);
  bf16* wqT = wqkvT;
  bf16* wkT = wqkvT + (size_t)Cn * Cn;
  bf16* wvT = wqkvT + (size_t)2 * Cn * Cn;
  bf16* woT = (bf16*)alloc((size_t)Cn * Cn * 2);
  bf16* fc1T = (bf16*)alloc((size_t)Fn * Cn * 2);
  bf16* fc2T = (bf16*)alloc((size_t)Cn * Fn * 2);
  bf16* xlnB = (bf16*)alloc(bnc * 2);             // LN1 out; later overlaid by mg (with qb)
  bf16* qb = (bf16*)alloc(bnc * 2);               // q -> attn-out (in-place)
  bf16* kb = (bf16*)alloc(bnc * 2);               // k; later overlaid by hbuf (with vb)
  bf16* vb = (bf16*)alloc(bnc * 2);               // v
  bf16* h2B = (bf16*)alloc((size_t)mrows * Cn * 2);
  double* mnD = (double*)alloc((size_t)rows * Dn * 8);
  double* wkavgD = (double*)alloc((size_t)Cn * Dn * 8);
  double* bkavgD = (double*)alloc((size_t)Dn * 8);
  float* stats1f = (float*)alloc((size_t)rows * 2 * 4);
  double* stats1d = (double*)alloc((size_t)rows * 2 * 8);
  float* stats2f = (float*)alloc((size_t)mrows * 2 * 4);
  double* nmaxD = (double*)alloc((size_t)Bn * NAn * 8);
  int* nidx = (int*)alloc((size_t)Bn * NAn * 4);
  int* unm  = (int*)alloc((size_t)Bn * UNMn * 4);
  int* srcI = (int*)alloc((size_t)Bn * Rn * 4);
  int* dstI = (int*)alloc((size_t)Bn * Rn * 4);
  float* cnt = (float*)alloc((size_t)Bn * NBn * 4);
  float* bqkv = (float*)alloc((size_t)3 * Cn * 4); // [SCALE*bq | bk | bv]
  // ffnB takes the REMAINING workspace (placed last).
  bf16* ffnB = (bf16*)(ws + off);
  size_t remain = (ws_size > off) ? (ws_size - off) : 0;
  size_t fullB = (size_t)mrows * Fn * 2;
  int CHUNK = (remain >= fullB) ? mrows : 2824;
  float* hbuf = (float*)kb;   // overlays kb+vb (dead after attn)
  float* mg   = (float*)xlnB; // overlays xlnB+qb (dead after QKV / wo-gemm)
  bf16* vtG   = ffnB;         // overlays ffnB (15.7MB; ffnB first written in step 9)
  double* kpartD = (double*)ffnB;  // overlays ffnB too (10.1MB; dead before vtG is written)

  // 0. Weight transpose+convert to bf16 [N][K]; wq gets SCALE folded in
  wconv_kernel<<<dim3(cdiv(Cn, 32), cdiv(Cn, 32)), 256, 0, stream>>>(wq, wqT, Cn, Cn, SCALEf);
  wconv_kernel<<<dim3(cdiv(Cn, 32), cdiv(Cn, 32)), 256, 0, stream>>>(wk, wkT, Cn, Cn, 1.f);
  wconv_kernel<<<dim3(cdiv(Cn, 32), cdiv(Cn, 32)), 256, 0, stream>>>(wv, wvT, Cn, Cn, 1.f);
  wconv_kernel<<<dim3(cdiv(Cn, 32), cdiv(Cn, 32)), 256, 0, stream>>>(wo, woT, Cn, Cn, 1.f);
  wconv_kernel<<<dim3(cdiv(Fn, 32), cdiv(Cn, 32)), 256, 0, stream>>>(fc1w, fc1T, Cn, Fn, 1.f);
  wconv_kernel<<<dim3(cdiv(Cn, 32), cdiv(Fn, 32)), 256, 0, stream>>>(fc2w, fc2T, Fn, Cn, 1.f);
  vscale_kernel<<<cdiv(Cn, 256), 256, 0, stream>>>(bq, bqkv, Cn, SCALEf);
  vscale_kernel<<<cdiv(Cn, 256), 256, 0, stream>>>(bk, bqkv + Cn, Cn, 1.f);
  vscale_kernel<<<cdiv(Cn, 256), 256, 0, stream>>>(bv, bqkv + 2 * Cn, Cn, 1.f);

  // 1. LN1 stats (fp32 + fp64)
  ln_stats_kernel<<<rows, 256, 0, stream>>>(hidden, stats1f, stats1d, rows);

  // 2. Decision path, all fp64 (split-K tiled GEMM + normalize)
  wkavg_kernel<<<Cn, 128, 0, stream>>>(wk, bk, wkavgD, bkavgD);
  metric_gemm_kernel<<<dim3(cdiv(rows, MT_ROWS), MT_SK), 256, 0, stream>>>(
      hidden, stats1d, ln1w, ln1b, wkavgD, kpartD, rows);
  metric_norm_kernel<<<rows, 128, 0, stream>>>(kpartD, bkavgD, mnD, rows);
  tome_score_kernel<<<Bn * NAn, 128, 0, stream>>>(mnD, nmaxD, nidx);
  tome_sort_kernel<<<Bn, 512, 0, stream>>>(nmaxD, nidx, unm, srcI, dstI, cnt);

  // 3. LN1 apply -> bf16
  ln_apply_kernel<<<rows, 256, 0, stream>>>(hidden, stats1f, ln1w, ln1b, xlnB);

  // 4. Fused QKV projection: one GEMM vs [3456][1152], epilogue routes to qb/kb/vb
  {
    int nx = cdiv(3 * Cn, 64), ny = cdiv(rows, 64);
    mfma_gemm<bf16, 64><<<nx * ny, 256, 0, stream>>>(xlnB, wqkvT, bqkv, nullptr,
                                                     qb, kb, vb, rows, 3 * Cn, Cn, 0);
  }

  // 4.5 One-shot V transpose into padded [b,h,80,768] layout
  vtrans_kernel<<<Bn * Hn * 12, 256, 0, stream>>>(vb, vtG);

  // 5. MFMA flash attention (in-place over q); round-4 body, T14 prefetch
  attn_mfma_kernel<<<Bn * Hn * NQT2, 256, 0, stream>>>(qb, kb, vtG, mask);

  // 6. Out-proj + residual(hidden) -> hbuf fp32 (overlays kb+vb)
  {
    int nx = cdiv(Cn, 64), ny = cdiv(rows, 64);
    mfma_gemm<float, 64><<<nx * ny, 256, 0, stream>>>(qb, woT, bo, hidden,
                                                      hbuf, nullptr, nullptr, rows, Cn, Cn, 0);
  }

  // 7. ToMe merge -> mg fp32 (overlays xlnB+qb)
  tome_merge_kernel<<<Bn * NMn, 256, 0, stream>>>(hbuf, unm, srcI, dstI, cnt, mg);

  // 8. LN2 stats + apply -> h2B bf16
  ln_stats_kernel<<<mrows, 256, 0, stream>>>(mg, stats2f, (double*)nullptr, mrows);
  ln_apply_kernel<<<mrows, 256, 0, stream>>>(mg, stats2f, ln2w, ln2b, h2B);

  // 9. MLP (bf16 MFMA); fc1 128-tiles, fc2 64-tiles; single-shot if workspace allows
  for (int c0 = 0; c0 < mrows; c0 += CHUNK) {
    int m = (mrows - c0 < CHUNK) ? (mrows - c0) : CHUNK;
    {
      int nx = cdiv(Fn, 128), ny = cdiv(m, 128);
      mfma_gemm<bf16, 128><<<nx * ny, 256, 0, stream>>>(h2B + (size_t)c0 * Cn, fc1T, fc1b,
                                                        nullptr, ffnB, nullptr, nullptr,
                                                        m, Fn, Cn, 1);
    }
    {
      int nx = cdiv(Cn, 64), ny = cdiv(m, 64);
      mfma_gemm<float, 64><<<nx * ny, 256, 0, stream>>>(ffnB, fc2T, fc2b, mg + (size_t)c0 * Cn,
                                                        out + (size_t)c0 * Cn, nullptr, nullptr,
                                                        m, Cn, Fn, 0);
    }
  }
}